// Round 3
// baseline (244.643 us; speedup 1.0000x reference)
//
#include <hip/hip_runtime.h>

#define NCOLS 1024  // N fixed at 1024 per reference setup

// Native clang vector type — accepted by __builtin_nontemporal_load/store.
typedef float vfloat4 __attribute__((ext_vector_type(4)));

// ---------------------------------------------------------------------------
// Two-pass structure: decouple the read stream from the write stream.
//
// Single-pass (R0-R2) topped out at ~4.3 TB/s combined: every wave must drain
// all its loads (vmcnt 0), run a 6-deep serial shuffle reduce, THEN store --
// the memory system sees bursty alternating R/W from every wave and never
// settles into a pure stream (fills on this same buffer prove 6.9 TB/s
// unidirectional). R2's counters showed FETCH_SIZE halved by L3 hits with no
// speedup -> reads are not the constraint; the R/W interleave is.
//
// K1: pure read-reduce (writes 128 KiB of inv factors to workspace). Cached
//     loads intentionally seed the 256 MiB L3 with the 128 MiB input.
// K2: re-read input (L3-resident now), scale, NT-store. Pure write stream to
//     HBM; NT stores don't evict the L3-resident input.
// ---------------------------------------------------------------------------

__global__ __launch_bounds__(256) void Normalizer_sum_kernel(
    const float* __restrict__ a0, const float* __restrict__ a1,
    float* __restrict__ inv_out, int rows_per_input) {
    const int lane = threadIdx.x & 63;
    const int wave = threadIdx.x >> 6;
    const int row  = blockIdx.x * 4 + wave;

    const float* src = (row < rows_per_input)
        ? a0 + (size_t)row * NCOLS
        : a1 + (size_t)(row - rows_per_input) * NCOLS;
    const vfloat4* s4 = reinterpret_cast<const vfloat4*>(src);

    // Cached (non-NT) loads: seed L3 for K2's re-read.
    vfloat4 v0 = s4[lane];
    vfloat4 v1 = s4[lane + 64];
    vfloat4 v2 = s4[lane + 128];
    vfloat4 v3 = s4[lane + 192];

    float s = ((v0.x + v0.y) + (v0.z + v0.w)) + ((v1.x + v1.y) + (v1.z + v1.w))
            + ((v2.x + v2.y) + (v2.z + v2.w)) + ((v3.x + v3.y) + (v3.z + v3.w));
#pragma unroll
    for (int off = 32; off > 0; off >>= 1)
        s += __shfl_xor(s, off, 64);

    float inv = 1.0f / s;
    if (!isfinite(inv)) inv = 0.0f;  // nan/inf -> 0 per reference

    if (lane == 0) inv_out[row] = inv;
}

__global__ __launch_bounds__(256) void Normalizer_scale_kernel(
    const float* __restrict__ a0, const float* __restrict__ a1,
    const float* __restrict__ inv_in, float* __restrict__ out,
    int rows_per_input) {
    const int lane = threadIdx.x & 63;
    const int wave = threadIdx.x >> 6;
    const int row  = blockIdx.x * 4 + wave;

    const float* src = (row < rows_per_input)
        ? a0 + (size_t)row * NCOLS
        : a1 + (size_t)(row - rows_per_input) * NCOLS;
    const vfloat4* s4 = reinterpret_cast<const vfloat4*>(src);

    // Wave-uniform broadcast load of the row's scale (one L2 line, trivial).
    const float inv = inv_in[row];

    // Cached loads: these lines were just streamed by K1 -> L3 hits.
    vfloat4 v0 = s4[lane];
    vfloat4 v1 = s4[lane + 64];
    vfloat4 v2 = s4[lane + 128];
    vfloat4 v3 = s4[lane + 192];

    // Output is the two normalized tensors concatenated -> row-major dst.
    vfloat4* d4 = reinterpret_cast<vfloat4*>(out + (size_t)row * NCOLS);
    __builtin_nontemporal_store(v0 * inv, &d4[lane]);
    __builtin_nontemporal_store(v1 * inv, &d4[lane + 64]);
    __builtin_nontemporal_store(v2 * inv, &d4[lane + 128]);
    __builtin_nontemporal_store(v3 * inv, &d4[lane + 192]);
}

// Fallback: R0 single-pass kernel (best single-pass config) in case the
// workspace is too small for the inv[] buffer.
__global__ __launch_bounds__(256) void Normalizer_row_kernel(
    const float* __restrict__ a0, const float* __restrict__ a1,
    float* __restrict__ out, int rows_per_input) {
    const int lane = threadIdx.x & 63;
    const int wave = threadIdx.x >> 6;
    const int row  = blockIdx.x * 4 + wave;

    const float* src = (row < rows_per_input)
        ? a0 + (size_t)row * NCOLS
        : a1 + (size_t)(row - rows_per_input) * NCOLS;
    const vfloat4* s4 = reinterpret_cast<const vfloat4*>(src);
    float* dst = out + (size_t)row * NCOLS;
    vfloat4* d4 = reinterpret_cast<vfloat4*>(dst);

    vfloat4 v0 = __builtin_nontemporal_load(&s4[lane]);
    vfloat4 v1 = __builtin_nontemporal_load(&s4[lane + 64]);
    vfloat4 v2 = __builtin_nontemporal_load(&s4[lane + 128]);
    vfloat4 v3 = __builtin_nontemporal_load(&s4[lane + 192]);

    float s = ((v0.x + v0.y) + (v0.z + v0.w)) + ((v1.x + v1.y) + (v1.z + v1.w))
            + ((v2.x + v2.y) + (v2.z + v2.w)) + ((v3.x + v3.y) + (v3.z + v3.w));
#pragma unroll
    for (int off = 32; off > 0; off >>= 1)
        s += __shfl_xor(s, off, 64);

    float inv = 1.0f / s;
    if (!isfinite(inv)) inv = 0.0f;

    __builtin_nontemporal_store(v0 * inv, &d4[lane]);
    __builtin_nontemporal_store(v1 * inv, &d4[lane + 64]);
    __builtin_nontemporal_store(v2 * inv, &d4[lane + 128]);
    __builtin_nontemporal_store(v3 * inv, &d4[lane + 192]);
}

extern "C" void kernel_launch(void* const* d_in, const int* in_sizes, int n_in,
                              void* d_out, int out_size, void* d_ws, size_t ws_size,
                              hipStream_t stream) {
    const float* a0 = (const float*)d_in[0];
    const float* a1 = (const float*)d_in[1];
    float* out = (float*)d_out;

    const int rows_per_input = in_sizes[0] / NCOLS;   // 16 * 1024 = 16384
    const int total_rows = 2 * rows_per_input;        // 32768
    const int blocks = total_rows / 4;                // 4 waves (rows) per block

    if (d_ws != nullptr && ws_size >= (size_t)total_rows * sizeof(float)) {
        float* inv_ws = (float*)d_ws;
        Normalizer_sum_kernel<<<blocks, 256, 0, stream>>>(
            a0, a1, inv_ws, rows_per_input);
        Normalizer_scale_kernel<<<blocks, 256, 0, stream>>>(
            a0, a1, inv_ws, out, rows_per_input);
    } else {
        Normalizer_row_kernel<<<blocks, 256, 0, stream>>>(
            a0, a1, out, rows_per_input);
    }
}

// Round 4
// 231.170 us; speedup vs baseline: 1.0583x; 1.0583x over previous
//
#include <hip/hip_runtime.h>

#define NCOLS 1024  // N fixed at 1024 per reference setup

typedef float vfloat4 __attribute__((ext_vector_type(4)));

// ---------------------------------------------------------------------------
// R4: A/B the two things every prior (4.3 TB/s) round held constant, against
// the two kernels measured at 6.3-6.9 TB/s on this chip (m13 float4 copy,
// rocclr fillBuffer): PLAIN stores (no nontemporal) + persistent grid-stride
// waves. R3 proved the bottleneck is not the reduce dependency (its
// dependency-free scale pass ran at the same 4.3 TB/s); R2 proved it is not
// the read side (L3 hits on half the reads, no speedup). The untested
// variables are the NT store path and one-shot wave churn.
//
// Structure: one wave per row per sweep; 2048 blocks x 4 waves = 8192
// persistent waves, each looping over 4 rows (grid-stride). Plain vector
// loads/stores throughout -- exactly the m13 copy recipe plus a butterfly
// row-sum.
// ---------------------------------------------------------------------------
__global__ __launch_bounds__(256) void Normalizer_row_kernel(
    const float* __restrict__ a0, const float* __restrict__ a1,
    float* __restrict__ out, int rows_per_input) {
    const int lane    = threadIdx.x & 63;
    const int wave    = threadIdx.x >> 6;
    const int nwaves  = gridDim.x << 2;               // waves in grid
    const int total   = rows_per_input * 2;

    for (int row = blockIdx.x * 4 + wave; row < total; row += nwaves) {
        const float* src = (row < rows_per_input)
            ? a0 + (size_t)row * NCOLS
            : a1 + (size_t)(row - rows_per_input) * NCOLS;
        const vfloat4* s4 = reinterpret_cast<const vfloat4*>(src);

        // Plain cached loads (m13-copy style), 4 KiB/wave, perfectly coalesced.
        vfloat4 v0 = s4[lane];
        vfloat4 v1 = s4[lane + 64];
        vfloat4 v2 = s4[lane + 128];
        vfloat4 v3 = s4[lane + 192];

        // Pairwise per-lane partial (16 values), then 6-step butterfly so
        // every lane ends with the full row sum.
        float s = ((v0.x + v0.y) + (v0.z + v0.w)) + ((v1.x + v1.y) + (v1.z + v1.w))
                + ((v2.x + v2.y) + (v2.z + v2.w)) + ((v3.x + v3.y) + (v3.z + v3.w));
#pragma unroll
        for (int off = 32; off > 0; off >>= 1)
            s += __shfl_xor(s, off, 64);

        float inv = 1.0f / s;
        if (!isfinite(inv)) inv = 0.0f;  // nan/inf -> 0 per reference

        // Plain stores: let L2 absorb and write back full bursts (the 6.9 TB/s
        // fill and 6.3 TB/s copy both store through L2; NT bypass was the one
        // flag every 4.3 TB/s variant shared).
        vfloat4* d4 = reinterpret_cast<vfloat4*>(out + (size_t)row * NCOLS);
        d4[lane]       = v0 * inv;
        d4[lane + 64]  = v1 * inv;
        d4[lane + 128] = v2 * inv;
        d4[lane + 192] = v3 * inv;
    }
}

extern "C" void kernel_launch(void* const* d_in, const int* in_sizes, int n_in,
                              void* d_out, int out_size, void* d_ws, size_t ws_size,
                              hipStream_t stream) {
    const float* a0 = (const float*)d_in[0];
    const float* a1 = (const float*)d_in[1];
    float* out = (float*)d_out;

    const int rows_per_input = in_sizes[0] / NCOLS;   // 16 * 1024 = 16384
    // 2048 blocks = 8 blocks/CU on 256 CUs; 8192 waves each sweep 4 rows.
    const int blocks = 2048;

    Normalizer_row_kernel<<<blocks, 256, 0, stream>>>(a0, a1, out, rows_per_input);
}

// Round 5
// 217.693 us; speedup vs baseline: 1.1238x; 1.0619x over previous
//
#include <hip/hip_runtime.h>

#define NCOLS 1024  // N fixed at 1024 per reference setup

// Native clang vector type — accepted by __builtin_nontemporal_load/store
// (HIP's float4 is a class and is rejected).
typedef float vfloat4 __attribute__((ext_vector_type(4)));

// R5 = exact revert to the best measured configuration (R0: 218.0 µs graded,
// ~62 µs kernel-side). The R1-R4 sweep tested: loop-carried prefetch (+3 µs),
// 2-row MLP + cached loads (+19), two-pass decoupled streams (+23), persistent
// grid-stride + cached load/store (+10). Everything regressed vs this config.
//
// One WAVE per row: 64 lanes x 4 vfloat4 = 1024 floats held in registers.
// Pure shuffle-butterfly reduction -- no LDS, no __syncthreads.
// Nontemporal loads AND stores: measurably the fastest path here (bypassing
// L2/L3 allocation avoids thrash against the harness fills' dirty lines;
// R2/R4 showed cached paths cost 10-19 µs).
__global__ __launch_bounds__(256) void Normalizer_row_kernel(
    const float* __restrict__ a0, const float* __restrict__ a1,
    float* __restrict__ out, int rows_per_input) {
    const int tid  = threadIdx.x;
    const int lane = tid & 63;
    const int wave = tid >> 6;
    const int row  = blockIdx.x * 4 + wave;   // global row in [0, 2*rows_per_input)

    // Output is the two normalized tensors concatenated: dst is simply row-major.
    const float* src = (row < rows_per_input)
        ? a0 + (size_t)row * NCOLS
        : a1 + (size_t)(row - rows_per_input) * NCOLS;
    float* dst = out + (size_t)row * NCOLS;

    const vfloat4* src4 = reinterpret_cast<const vfloat4*>(src);
    vfloat4* dst4 = reinterpret_cast<vfloat4*>(dst);

    // 4 independent 16B loads per lane (ILP), perfectly coalesced 1 KiB/wave each.
    vfloat4 v0 = __builtin_nontemporal_load(&src4[lane]);
    vfloat4 v1 = __builtin_nontemporal_load(&src4[lane + 64]);
    vfloat4 v2 = __builtin_nontemporal_load(&src4[lane + 128]);
    vfloat4 v3 = __builtin_nontemporal_load(&src4[lane + 192]);

    // Pairwise per-lane partial sum (16 values), then 6-step butterfly so
    // every lane ends with the full row sum (no broadcast needed).
    float s = ((v0.x + v0.y) + (v0.z + v0.w)) + ((v1.x + v1.y) + (v1.z + v1.w))
            + ((v2.x + v2.y) + (v2.z + v2.w)) + ((v3.x + v3.y) + (v3.z + v3.w));
#pragma unroll
    for (int off = 32; off > 0; off >>= 1)
        s += __shfl_xor(s, off, 64);

    float inv = 1.0f / s;
    if (!isfinite(inv)) inv = 0.0f;  // nan/inf -> 0 per reference

    v0 *= inv;
    v1 *= inv;
    v2 *= inv;
    v3 *= inv;

    __builtin_nontemporal_store(v0, &dst4[lane]);
    __builtin_nontemporal_store(v1, &dst4[lane + 64]);
    __builtin_nontemporal_store(v2, &dst4[lane + 128]);
    __builtin_nontemporal_store(v3, &dst4[lane + 192]);
}

extern "C" void kernel_launch(void* const* d_in, const int* in_sizes, int n_in,
                              void* d_out, int out_size, void* d_ws, size_t ws_size,
                              hipStream_t stream) {
    const float* a0 = (const float*)d_in[0];
    const float* a1 = (const float*)d_in[1];
    float* out = (float*)d_out;

    const int rows_per_input = in_sizes[0] / NCOLS;  // 16 * 1024 = 16384
    const int total_rows = 2 * rows_per_input;       // 32768
    const int blocks = total_rows / 4;               // 4 waves (rows) per block

    Normalizer_row_kernel<<<blocks, 256, 0, stream>>>(a0, a1, out, rows_per_input);
}